// Round 9
// baseline (7887.833 us; speedup 1.0000x reference)
//
#include <hip/hip_runtime.h>
#include <math.h>

#define T_SEQ 4096

typedef unsigned long long u64;
typedef unsigned int v4u __attribute__((ext_vector_type(4)));

__device__ __forceinline__ float sigmoidf_(float x) {
  return 1.0f / (1.0f + expf(-x));
}

__device__ __forceinline__ u64 pack_h(int tag, float h) {
  return ((u64)(unsigned)tag << 32) | (u64)__float_as_uint(h);
}

// Self-contained 16B device-truth probe (issue + wait in ONE asm block: no
// in-flight-register hazard). Covers 2 tagged u64 words.
__device__ __forceinline__ v4u probe16(const u64* p) {
  v4u v;
  asm volatile("global_load_dwordx4 %0, %1, off sc0 sc1\n\ts_waitcnt vmcnt(0)"
               : "=v"(v) : "v"(p) : "memory");
  return v;
}
// Device-coherent 8B publish store.
__device__ __forceinline__ void st_mall(u64* p, u64 v) {
  asm volatile("global_store_dwordx2 %0, %1, off sc0 sc1"
               :: "v"(p), "v"(v) : "memory");
}
__device__ __forceinline__ void half_rt_sleep() {
  asm volatile("s_sleep 7" ::: "memory");   // ~448 cycles
}

// Poll 2 words from a private mailbox slot; if the slot shows a FUTURE tag
// (consumer lagged >15 steps, slot overwritten), read the archive ring entry,
// which is guaranteed long-published. Hang-free under all schedules.
__device__ __forceinline__ void poll2(const u64* pvt, const u64* arch,
                                      unsigned want, float* d0, float* d1) {
  for (;;) {
    v4u v = probe16(pvt);
    if (v[1] == want && v[3] == want) {
      *d0 = __uint_as_float(v[0]); *d1 = __uint_as_float(v[2]); return;
    }
    if (v[1] > want || v[3] > want) {
      for (;;) {
        v4u a = probe16(arch);
        if (a[1] == want && a[3] == want) {
          *d0 = __uint_as_float(a[0]); *d1 = __uint_as_float(a[2]); return;
        }
      }
    }
  }
}
// Same, no archive (h1 mailboxes: sibling skew is protocol-bounded to 1).
__device__ __forceinline__ void poll2n(const u64* pvt, unsigned want,
                                       float* d0, float* d1) {
  for (;;) {
    v4u v = probe16(pvt);
    if (v[1] == want && v[3] == want) {
      *d0 = __uint_as_float(v[0]); *d1 = __uint_as_float(v[2]); return;
    }
  }
}

// X[t][k] = emb[tokens[t]][k], as float4
__global__ void gather_emb(const int* __restrict__ tokens,
                           const float4* __restrict__ emb4,
                           float4* __restrict__ X4) {
  int i = blockIdx.x * 256 + threadIdx.x;   // i < 4096*128
  int t = i >> 7;
  int q = i & 127;
  X4[i] = emb4[(long)tokens[t] * 128 + q];
}

// P[t][j] = bias_ih[j] + bias_hh[j] + sum_k X[src(t)][k] * W[j][k]
__global__ __launch_bounds__(256) void gemm_proj(
    const float* __restrict__ Xf, const float* __restrict__ Xb, int revb,
    const float* __restrict__ Wf, const float* __restrict__ Wb,
    const float* __restrict__ bihf, const float* __restrict__ bhhf,
    const float* __restrict__ bihb, const float* __restrict__ bhhb,
    float* __restrict__ Pf, float* __restrict__ Pb, int K)
{
  const int dirb = blockIdx.z;
  const float* X  = dirb ? Xb : Xf;
  const float* W  = dirb ? Wb : Wf;
  const float* bih = dirb ? bihb : bihf;
  const float* bhh = dirb ? bhhb : bhhf;
  float* Pp = dirb ? Pb : Pf;
  const int rev = dirb ? revb : 0;

  const int bn = blockIdx.x;   // N tile (16)
  const int bm = blockIdx.y;   // M tile (64)
  const int tid = threadIdx.x;
  const int tx = tid & 15, ty = tid >> 4;

  __shared__ float Xs[16][68];
  __shared__ float Ws[16][68];

  float acc[4][4] = {{0.f}};

  const int lrow = tid >> 2;
  const int lk4  = (tid & 3) * 4;
  const int xrow = bm * 64 + lrow;
  const int xsrc = rev ? (4095 - xrow) : xrow;
  const float* xptr = X + (long)xsrc * K + lk4;
  const float* wptr = W + (long)(bn * 64 + lrow) * K + lk4;

  for (int k0 = 0; k0 < K; k0 += 16) {
    float4 xv = *(const float4*)(xptr + k0);
    float4 wv = *(const float4*)(wptr + k0);
    __syncthreads();
    Xs[lk4 + 0][lrow] = xv.x; Xs[lk4 + 1][lrow] = xv.y;
    Xs[lk4 + 2][lrow] = xv.z; Xs[lk4 + 3][lrow] = xv.w;
    Ws[lk4 + 0][lrow] = wv.x; Ws[lk4 + 1][lrow] = wv.y;
    Ws[lk4 + 2][lrow] = wv.z; Ws[lk4 + 3][lrow] = wv.w;
    __syncthreads();
    #pragma unroll
    for (int kk = 0; kk < 16; ++kk) {
      float4 a = *(const float4*)(&Xs[kk][ty * 4]);
      float4 b = *(const float4*)(&Ws[kk][tx * 4]);
      acc[0][0] = fmaf(a.x, b.x, acc[0][0]); acc[0][1] = fmaf(a.x, b.y, acc[0][1]);
      acc[0][2] = fmaf(a.x, b.z, acc[0][2]); acc[0][3] = fmaf(a.x, b.w, acc[0][3]);
      acc[1][0] = fmaf(a.y, b.x, acc[1][0]); acc[1][1] = fmaf(a.y, b.y, acc[1][1]);
      acc[1][2] = fmaf(a.y, b.z, acc[1][2]); acc[1][3] = fmaf(a.y, b.w, acc[1][3]);
      acc[2][0] = fmaf(a.z, b.x, acc[2][0]); acc[2][1] = fmaf(a.z, b.y, acc[2][1]);
      acc[2][2] = fmaf(a.z, b.z, acc[2][2]); acc[2][3] = fmaf(a.z, b.w, acc[2][3]);
      acc[3][0] = fmaf(a.w, b.x, acc[3][0]); acc[3][1] = fmaf(a.w, b.y, acc[3][1]);
      acc[3][2] = fmaf(a.w, b.z, acc[3][2]); acc[3][3] = fmaf(a.w, b.w, acc[3][3]);
    }
  }

  const int c0 = bn * 64 + tx * 4;
  #pragma unroll
  for (int i = 0; i < 4; ++i) {
    const int r = bm * 64 + ty * 4 + i;
    float4 o4;
    o4.x = acc[i][0] + bih[c0 + 0] + bhh[c0 + 0];
    o4.y = acc[i][1] + bih[c0 + 1] + bhh[c0 + 1];
    o4.z = acc[i][2] + bih[c0 + 2] + bhh[c0 + 2];
    o4.w = acc[i][3] + bih[c0 + 3] + bhh[c0 + 3];
    *(float4*)(&Pp[(long)r * 1024 + c0]) = o4;
  }
}

// Fused 2-layer bidirectional LSTM recurrence. 24 WGs x 512 threads.
//   bx 0..7  : L0 (4/dir, 64 cells each)   bx 8..23 : L1 (8/dir, 32 cells)
// Exchange via PRIVATE per-consumer mailboxes (depth-16 tagged slot rings) so
// no two WGs ever poll the same cacheline -> no MALL hot-line queueing.
// Producers fan out h to every consumer's mailbox + the shared archive ring
// (fallback for lagging consumers -> hang-free). Consumers poll with
// self-contained dwordx4 MALL probes; a second poller group runs a half-RT
// antiphase (s_sleep) so the words are sampled every ~450 cycles.
__global__ __launch_bounds__(512, 2) void lstm_fused(
    const float* __restrict__ P0f, const float* __restrict__ P0b,
    const float* __restrict__ Whh0f, const float* __restrict__ Whh0b,
    const float* __restrict__ Wih1f, const float* __restrict__ Whh1f,
    const float* __restrict__ bih1f, const float* __restrict__ bhh1f,
    const float* __restrict__ Wih1b, const float* __restrict__ Whh1b,
    const float* __restrict__ bih1b, const float* __restrict__ bhh1b,
    float* __restrict__ out,
    u64* __restrict__ ring0,   // archive: [2][4096][256]
    u64* __restrict__ pvt0,    // h0 mailboxes: [2][12 consumers][16][256]
    u64* __restrict__ pvt1)    // h1 mailboxes: [2][8 consumers][16][256]
{
  const int bx = blockIdx.x;
  const int t  = threadIdx.x;

  __shared__ float hx[512];        // L0: h0[256]; L1: h0[s] ++ h1[s-1]
  __shared__ float part[8 * 264];  // [k-slice][row], padded
  __shared__ float gact[256];      // activated gates
  __shared__ float lds_c[64];

  if (t < 64) lds_c[t] = 0.0f;

  if (bx < 8) {
    // ======================= Layer 0 =======================
    const int d = bx >> 2, w = bx & 3;
    const float* __restrict__ P = d ? P0b : P0f;
    const float* __restrict__ W = d ? Whh0b : Whh0f;
    u64* arch  = ring0 + (long)d * T_SEQ * 256;
    u64* pvtd  = pvt0 + (long)d * 12 * 16 * 256;
    const u64* mybuf = pvtd + (long)w * 16 * 256;   // consumer index w

    const int kb = t >> 6;   // k-slice 0..7 (32 k each)
    const int jg = t & 63;   // -> 4 rows m = jg*4..+3

    float wreg[128];
    #pragma unroll
    for (int jj = 0; jj < 4; ++jj) {
      const int m = jg * 4 + jj;
      const int j = (m >> 6) * 256 + w * 64 + (m & 63);
      const float4* wrow = (const float4*)(W + (long)j * 256 + kb * 32);
      #pragma unroll
      for (int kq = 0; kq < 8; ++kq) {
        float4 v = wrow[kq];
        wreg[jj * 32 + kq * 4 + 0] = v.x;
        wreg[jj * 32 + kq * 4 + 1] = v.y;
        wreg[jj * 32 + kq * 4 + 2] = v.z;
        wreg[jj * 32 + kq * 4 + 3] = v.w;
      }
    }

    const long pj   = (long)((t >> 6) * 256 + w * 64 + (t & 63));  // t<256
    const int  cell = w * 64 + (t & 63);                           // t<64

    for (int s = 0; s < T_SEQ; ++s) {
      float pval = 0.0f;
      if (t < 256) pval = P[(long)s * 1024 + pj];   // prefetch before poll

      if (s == 0) {
        if (t < 256) hx[t] = 0.0f;
      } else if (t < 256) {
        // words 2i,2i+1; primary = t<128 (i=t), antiphase = t in [128,256)
        const int i = t & 127;
        const int wi = i * 2;
        if ((wi >> 6) != w) {            // own words written at finalize
          if (t >= 128) half_rt_sleep();
          const int slot = (s - 1) & 15;
          poll2(mybuf + slot * 256 + wi, arch + (long)(s - 1) * 256 + wi,
                (unsigned)s, &hx[wi], &hx[wi + 1]);
        }
      }
      __syncthreads();

      float a0 = 0.f, a1 = 0.f, a2 = 0.f, a3 = 0.f;
      const float4* h4 = (const float4*)&hx[kb * 32];
      #pragma unroll
      for (int kq = 0; kq < 8; ++kq) {
        float4 hv = h4[kq];
        a0 = fmaf(wreg[0 * 32 + kq * 4 + 0], hv.x, a0);
        a0 = fmaf(wreg[0 * 32 + kq * 4 + 1], hv.y, a0);
        a0 = fmaf(wreg[0 * 32 + kq * 4 + 2], hv.z, a0);
        a0 = fmaf(wreg[0 * 32 + kq * 4 + 3], hv.w, a0);
        a1 = fmaf(wreg[1 * 32 + kq * 4 + 0], hv.x, a1);
        a1 = fmaf(wreg[1 * 32 + kq * 4 + 1], hv.y, a1);
        a1 = fmaf(wreg[1 * 32 + kq * 4 + 2], hv.z, a1);
        a1 = fmaf(wreg[1 * 32 + kq * 4 + 3], hv.w, a1);
        a2 = fmaf(wreg[2 * 32 + kq * 4 + 0], hv.x, a2);
        a2 = fmaf(wreg[2 * 32 + kq * 4 + 1], hv.y, a2);
        a2 = fmaf(wreg[2 * 32 + kq * 4 + 2], hv.z, a2);
        a2 = fmaf(wreg[2 * 32 + kq * 4 + 3], hv.w, a2);
        a3 = fmaf(wreg[3 * 32 + kq * 4 + 0], hv.x, a3);
        a3 = fmaf(wreg[3 * 32 + kq * 4 + 1], hv.y, a3);
        a3 = fmaf(wreg[3 * 32 + kq * 4 + 2], hv.z, a3);
        a3 = fmaf(wreg[3 * 32 + kq * 4 + 3], hv.w, a3);
      }
      float4 av; av.x = a0; av.y = a1; av.z = a2; av.w = a3;
      *(float4*)(&part[kb * 264 + jg * 4]) = av;
      __syncthreads();

      if (t < 256) {   // parallel gate activation: 1 transcendental/thread
        float g = pval;
        #pragma unroll
        for (int q = 0; q < 8; ++q) g += part[q * 264 + t];
        gact[t] = ((t >> 6) == 2) ? tanhf(g) : sigmoidf_(g);
      }
      __syncthreads();

      if (t < 64) {    // finalize + fan-out publish
        float c = gact[64 + t] * lds_c[t] + gact[t] * gact[128 + t];
        float h = gact[192 + t] * tanhf(c);
        lds_c[t] = c;
        hx[cell] = h;                       // own words for next step's matvec
        const u64 pk = pack_h(s + 1, h);
        u64* base = pvtd + (long)(s & 15) * 256 + cell;
        #pragma unroll
        for (int cns = 0; cns < 12; ++cns)
          st_mall(base + (long)cns * 4096, pk);   // 12 consumer mailboxes
        st_mall(arch + (long)s * 256 + cell, pk); // archive
        if (s == T_SEQ - 1) {
          out[d * 256 + cell] = c;           // cell_memories layer 0
          out[1024 + d * 256 + cell] = h;    // hidden_states layer 0
        }
      }
    }
  } else {
    // ======================= Layer 1 =======================
    const int i1 = bx - 8, d = i1 >> 3, w1 = i1 & 7;
    const float* __restrict__ Wih = d ? Wih1b : Wih1f;
    const float* __restrict__ Whh = d ? Whh1b : Whh1f;
    const float* __restrict__ bih = d ? bih1b : bih1f;
    const float* __restrict__ bhh = d ? bhh1b : bhh1f;
    u64* arch = ring0 + (long)d * T_SEQ * 256;
    const u64* myh0 = pvt0 + (long)(d * 12 + 4 + w1) * 16 * 256;
    u64* pvt1d = pvt1 + (long)d * 8 * 16 * 256;
    const u64* myh1 = pvt1d + (long)w1 * 16 * 256;
    float* hout = d ? (out + 2048 + (long)4095 * 512 + 256) : (out + 2048);
    const long hstr = d ? -512 : 512;

    const int kb = t >> 6;   // k-slice 0..7 (64 k each of combined K=512)
    const int jg = t & 63;   // -> 2 rows m = jg*2, jg*2+1

    float wreg[2][64];
    #pragma unroll
    for (int rr = 0; rr < 2; ++rr) {
      const int m = jg * 2 + rr;
      const int j = (m >> 5) * 256 + w1 * 32 + (m & 31);
      const float* srcw = (kb < 4) ? (Wih + (long)j * 256 + kb * 64)
                                   : (Whh + (long)j * 256 + (kb - 4) * 64);
      const float4* s4 = (const float4*)srcw;
      #pragma unroll
      for (int q = 0; q < 16; ++q) {
        float4 v = s4[q];
        wreg[rr][q * 4 + 0] = v.x; wreg[rr][q * 4 + 1] = v.y;
        wreg[rr][q * 4 + 2] = v.z; wreg[rr][q * 4 + 3] = v.w;
      }
    }

    const int cell = w1 * 32 + (t & 31);   // t<32
    float bsum = 0.0f;
    if (t < 128) {
      const int j = (t >> 5) * 256 + w1 * 32 + (t & 31);
      bsum = bih[j] + bhh[j];
    }

    for (int s = 0; s < T_SEQ; ++s) {
      if (t < 256) {
        // h0[s] from my mailbox (tag s+1), archive fallback.
        const int i = t & 127;
        const int wi = i * 2;
        if (t >= 128) half_rt_sleep();
        poll2(myh0 + (long)(s & 15) * 256 + wi, arch + (long)s * 256 + wi,
              (unsigned)(s + 1), &hx[wi], &hx[wi + 1]);
      } else {
        // h1[s-1] from sibling mailboxes (tag s); skew <= 1 by protocol.
        const int i = (t - 256) & 127;
        const int wi = i * 2;
        if (s == 0) {
          hx[256 + wi] = 0.0f; hx[257 + wi] = 0.0f;
        } else if ((wi >> 5) != w1) {      // own words written at finalize
          if (t >= 384) half_rt_sleep();
          poll2n(myh1 + (long)((s - 1) & 15) * 256 + wi, (unsigned)s,
                 &hx[256 + wi], &hx[257 + wi]);
        }
      }
      __syncthreads();

      float a0 = 0.f, a1 = 0.f;
      const float4* h4 = (const float4*)&hx[kb * 64];
      #pragma unroll
      for (int q = 0; q < 16; ++q) {
        float4 hv = h4[q];
        a0 = fmaf(wreg[0][q * 4 + 0], hv.x, a0);
        a0 = fmaf(wreg[0][q * 4 + 1], hv.y, a0);
        a0 = fmaf(wreg[0][q * 4 + 2], hv.z, a0);
        a0 = fmaf(wreg[0][q * 4 + 3], hv.w, a0);
        a1 = fmaf(wreg[1][q * 4 + 0], hv.x, a1);
        a1 = fmaf(wreg[1][q * 4 + 1], hv.y, a1);
        a1 = fmaf(wreg[1][q * 4 + 2], hv.z, a1);
        a1 = fmaf(wreg[1][q * 4 + 3], hv.w, a1);
      }
      float2 av2; av2.x = a0; av2.y = a1;
      *(float2*)(&part[kb * 264 + jg * 2]) = av2;
      __syncthreads();

      if (t < 128) {   // parallel gate activation
        float g = bsum;
        #pragma unroll
        for (int q = 0; q < 8; ++q) g += part[q * 264 + t];
        gact[t] = ((t >> 5) == 2) ? tanhf(g) : sigmoidf_(g);
      }
      __syncthreads();

      if (t < 32) {    // finalize + fan-out publish
        float c = gact[32 + t] * lds_c[t] + gact[t] * gact[64 + t];
        float h = gact[96 + t] * tanhf(c);
        lds_c[t] = c;
        hx[256 + cell] = h;                 // own words for next step
        const u64 pk = pack_h(s + 1, h);
        u64* base = pvt1d + (long)(s & 15) * 256 + cell;
        #pragma unroll
        for (int cns = 0; cns < 8; ++cns)
          st_mall(base + (long)cns * 4096, pk);   // 8 sibling mailboxes
        hout[(long)s * hstr + cell] = h;
        if (s == T_SEQ - 1) {
          out[512 + d * 256 + cell] = c;          // cell_memories layer 1
          out[1024 + 512 + d * 256 + cell] = h;   // hidden_states layer 1
        }
      }
    }
  }
}

extern "C" void kernel_launch(void* const* d_in, const int* in_sizes, int n_in,
                              void* d_out, int out_size, void* d_ws, size_t ws_size,
                              hipStream_t stream) {
  const int*   tokens = (const int*)d_in[0];
  const float* emb    = (const float*)d_in[1];
  const float* fWih0 = (const float*)d_in[2];
  const float* fWhh0 = (const float*)d_in[3];
  const float* fbih0 = (const float*)d_in[4];
  const float* fbhh0 = (const float*)d_in[5];
  const float* fWih1 = (const float*)d_in[6];
  const float* fWhh1 = (const float*)d_in[7];
  const float* fbih1 = (const float*)d_in[8];
  const float* fbhh1 = (const float*)d_in[9];
  const float* bWih0 = (const float*)d_in[10];
  const float* bWhh0 = (const float*)d_in[11];
  const float* bbih0 = (const float*)d_in[12];
  const float* bbhh0 = (const float*)d_in[13];
  const float* bWih1 = (const float*)d_in[14];
  const float* bWhh1 = (const float*)d_in[15];
  const float* bbih1 = (const float*)d_in[16];
  const float* bbhh1 = (const float*)d_in[17];

  float* out = (float*)d_out;
  float* ws  = (float*)d_ws;

  // Workspace layout (float offsets):
  //   [0, 4194304)          archive rings: [2][4096][256] u64 (16 MB).
  //                         X (4096x512, 8 MB) overlaps — dead after gemm_proj.
  //   [4194304,  8388608)   P0f (4096x1024)
  //   [8388608, 12582912)   P0b (4096x1024)
  //   [12582912, 12779520)  pvt0: [2][12][16][256] u64 (768 KB)
  //   [12779520, 12910592)  pvt1: [2][8][16][256] u64 (512 KB)
  float* X   = ws;
  float* P0f = ws + 4194304;
  float* P0b = ws + 8388608;
  u64* ring0 = (u64*)ws;
  u64* pvt0  = (u64*)(ws + 12582912);
  u64* pvt1  = (u64*)(ws + 12779520);

  gather_emb<<<2048, 256, 0, stream>>>(tokens, (const float4*)emb, (float4*)X);

  // Layer 0 input projections (K=512); b-direction reads X time-reversed.
  gemm_proj<<<dim3(16, 64, 2), 256, 0, stream>>>(
      X, X, 1, fWih0, bWih0, fbih0, fbhh0, bbih0, bbhh0, P0f, P0b, 512);

  // Zero archive rings + mailboxes (tag 0 = "not ready").
  hipMemsetAsync(ring0, 0, (size_t)2 * T_SEQ * 256 * sizeof(u64), stream);
  hipMemsetAsync(pvt0, 0, (size_t)(98304 + 65536) * sizeof(u64), stream);

  // Fused 2-layer bidirectional recurrence: 8 L0 WGs + 16 L1 WGs.
  lstm_fused<<<dim3(24), 512, 0, stream>>>(
      P0f, P0b, fWhh0, bWhh0,
      fWih1, fWhh1, fbih1, fbhh1,
      bWih1, bWhh1, bbih1, bbhh1,
      out, ring0, pvt0, pvt1);
}